// Round 10
// baseline (54.858 us; speedup 1.0000x reference)
//
#include <hip/hip_runtime.h>
#include <hip/hip_bf16.h>
#include <math.h>
#include <stdint.h>

#define NS 8192       // samples
#define DD 1024       // feature dim
#define NP 512        // prototypes
#define BK 128        // K-chunk (8 iterations)
#define MT 64         // M rows per block
#define NT 128        // N cols per block
#define NPARTS 8      // 4 N-blocks * 2 wave-col-halves
#define EPSF 1e-9f
#define BIGF 3.0e38f

typedef __attribute__((ext_vector_type(8))) short bf16x8;
typedef __attribute__((ext_vector_type(4))) float f32x4;

__device__ inline unsigned short f32_to_bf16(float f) {
    uint32_t u = __builtin_bit_cast(uint32_t, f);
    uint32_t r = (u + 0x7FFFu + ((u >> 16) & 1u)) >> 16;
    return (unsigned short)r;
}

__device__ inline uint32_t cvt_pk(float lo, float hi) {
    uint32_t r;
    asm("v_cvt_pk_bf16_f32 %0, %1, %2" : "=v"(r) : "v"(lo), "v"(hi));
    return r;
}

// protos f32 -> bf16 (pb) + exact f32 psq. One block per prototype row.
__global__ __launch_bounds__(256) void prep_protos(
    const float* __restrict__ protos,
    unsigned short* __restrict__ pb, float* __restrict__ psq)
{
    const int row = blockIdx.x;
    const int t = threadIdx.x;
    float4 v = ((const float4*)(protos + (size_t)row * DD))[t];
    float ss = v.x * v.x + v.y * v.y + v.z * v.z + v.w * v.w;
    ushort4 o;
    o.x = f32_to_bf16(v.x); o.y = f32_to_bf16(v.y);
    o.z = f32_to_bf16(v.z); o.w = f32_to_bf16(v.w);
    ((ushort4*)(pb + (size_t)row * DD))[t] = o;
    for (int off = 32; off; off >>= 1) ss += __shfl_down(ss, off);
    __shared__ float red[4];
    if ((t & 63) == 0) red[t >> 6] = ss;
    __syncthreads();
    if (t == 0) psq[row] = red[0] + red[1] + red[2] + red[3];
}

// Per-kk compute: B frags from swizzled LDS, A frags converted in-reg from f32.
#define COMPUTE(AS, BUF)                                                         \
    _Pragma("unroll")                                                            \
    for (int kk = 0; kk < 4; ++kk) {                                             \
        bf16x8 bfr[4];                                                           \
        _Pragma("unroll")                                                        \
        for (int n = 0; n < 4; ++n) {                                            \
            const int rowb = wc * 64 + n * 16 + sub;                             \
            const int c16 = (kk * 4 + g) ^ (rowb & 15);                          \
            bfr[n] = *(const bf16x8*)((const char*)&Bs[BUF][0] + rowb * 256 + c16 * 16); \
        }                                                                        \
        _Pragma("unroll")                                                        \
        for (int m = 0; m < 2; ++m) {                                            \
            float4 u = AS[kk * 4 + m * 2], v = AS[kk * 4 + m * 2 + 1];           \
            if (wc == 0) {                                                       \
                float s = u.x*u.x + u.y*u.y + u.z*u.z + u.w*u.w                  \
                        + v.x*v.x + v.y*v.y + v.z*v.z + v.w*v.w;                 \
                if (m == 0) xss0 += s; else xss1 += s;                           \
            }                                                                    \
            uint4 t;                                                             \
            t.x = cvt_pk(u.x, u.y); t.y = cvt_pk(u.z, u.w);                      \
            t.z = cvt_pk(v.x, v.y); t.w = cvt_pk(v.z, v.w);                      \
            bf16x8 afr = __builtin_bit_cast(bf16x8, t);                          \
            _Pragma("unroll")                                                    \
            for (int n = 0; n < 4; ++n)                                          \
                acc[m][n] = __builtin_amdgcn_mfma_f32_16x16x32_bf16(afr, bfr[n], acc[m][n], 0, 0, 0); \
        }                                                                        \
    }

// Fused GEMM+min. BK=128 (8 iters). A: direct global->reg f32, cvt_pk->bf16
// fragments (no A LDS, no ds_write, no lgkm in loop). B: global_load_lds into
// XOR-swizzled dbuf LDS with ONE counted vmcnt(16) + ONE barrier per iter.
// 64x128 tile, 4 waves (2Mx2N), grid 512 (2 blocks/CU), XCD-bijective.
__global__ __launch_bounds__(256, 2) void glvq_fused(
    const float* __restrict__ x, const unsigned short* __restrict__ pb,
    const float* __restrict__ psq, const int* __restrict__ y,
    float* __restrict__ d1p, float* __restrict__ d2p)
{
    __shared__ unsigned short Bs[2][NT * BK];   // 2 x 32 KB
    __shared__ float xs_l[MT];

    const int tid  = threadIdx.x;
    const int lane = tid & 63;
    const int wid  = tid >> 6;        // 0..3
    const int wr = wid >> 1;
    const int wc = wid & 1;
    const int d    = blockIdx.x;      // 0..511
    const int xcd  = d & 7;
    const int slot = d >> 3;
    const int mb   = xcd * 16 + (slot & 15);
    const int nb   = slot >> 4;
    const int m0   = mb * MT;
    const int n0   = nb * NT;

    const int sub = lane & 15, g = lane >> 4;

    f32x4 acc[2][4] = {};
    float xss0 = 0.0f, xss1 = 0.0f;
    float4 as0[16], as1[16];          // two static A register sets (f32)

    const float* xr0 = x + (size_t)(m0 + wr * 32 + sub) * DD;        // m=0 row
    const float* xr1 = x + (size_t)(m0 + wr * 32 + 16 + sub) * DD;   // m=1 row

    auto stageB = [&](int buf, int kt) {
        const int k0 = kt * BK;
#pragma unroll
        for (int j = 0; j < 8; ++j) {
            const int rbase = wid * 32 + j * 4;            // 4 rows per inst
            const int r = rbase + (lane >> 4);
            const int c16 = (lane & 15) ^ (r & 15);        // pre-swizzled source chunk
            const unsigned short* gb = pb + (size_t)(n0 + r) * DD + k0 + c16 * 8;
            __builtin_amdgcn_global_load_lds(
                (const __attribute__((address_space(1))) void*)gb,
                (__attribute__((address_space(3))) void*)((char*)&Bs[buf][0] + rbase * 256),
                16, 0, 0);
        }
    };
    auto loadA0 = [&](int kt) {
#pragma unroll
        for (int kk = 0; kk < 4; ++kk) {
            const float* p0 = xr0 + kt * BK + kk * 32 + g * 8;
            const float* p1 = xr1 + kt * BK + kk * 32 + g * 8;
            as0[kk * 4 + 0] = *(const float4*)(p0);
            as0[kk * 4 + 1] = *(const float4*)(p0 + 4);
            as0[kk * 4 + 2] = *(const float4*)(p1);
            as0[kk * 4 + 3] = *(const float4*)(p1 + 4);
        }
    };
    auto loadA1 = [&](int kt) {
#pragma unroll
        for (int kk = 0; kk < 4; ++kk) {
            const float* p0 = xr0 + kt * BK + kk * 32 + g * 8;
            const float* p1 = xr1 + kt * BK + kk * 32 + g * 8;
            as1[kk * 4 + 0] = *(const float4*)(p0);
            as1[kk * 4 + 1] = *(const float4*)(p0 + 4);
            as1[kk * 4 + 2] = *(const float4*)(p1);
            as1[kk * 4 + 3] = *(const float4*)(p1 + 4);
        }
    };

    // prologue: A(0) [16 loads] then B(0) [8 loads] in flight
    loadA0(0);
    stageB(0, 0);

    // Ledger per iter: in-flight order A(kt),B(kt),A(kt+1); vmcnt(16) drains
    // A(kt)+B(kt), leaves A(kt+1). Stage AFTER barrier (dbuf race-safe: target
    // buffer's last readers are before the PREVIOUS barrier).
#pragma unroll 1
    for (int kt = 0; kt < 6; kt += 2) {
        // even sub-iter: compute set0/buf0
        loadA1(kt + 1);
        asm volatile("s_waitcnt vmcnt(16)" ::: "memory");
        __builtin_amdgcn_s_barrier();
        stageB(1, kt + 1);
        __builtin_amdgcn_s_setprio(1);
        COMPUTE(as0, 0);
        __builtin_amdgcn_s_setprio(0);
        // odd sub-iter: compute set1/buf1
        loadA0(kt + 2);
        asm volatile("s_waitcnt vmcnt(16)" ::: "memory");
        __builtin_amdgcn_s_barrier();
        stageB(0, kt + 2);
        __builtin_amdgcn_s_setprio(1);
        COMPUTE(as1, 1);
        __builtin_amdgcn_s_setprio(0);
    }
    // kt = 6
    loadA1(7);
    asm volatile("s_waitcnt vmcnt(16)" ::: "memory");
    __builtin_amdgcn_s_barrier();
    stageB(1, 7);
    __builtin_amdgcn_s_setprio(1);
    COMPUTE(as0, 0);
    __builtin_amdgcn_s_setprio(0);
    // kt = 7 (peel: drain everything)
    asm volatile("s_waitcnt vmcnt(0)" ::: "memory");
    __builtin_amdgcn_s_barrier();
    __builtin_amdgcn_s_setprio(1);
    COMPUTE(as1, 1);
    __builtin_amdgcn_s_setprio(0);

    // exact xsq: each (row, k-slice) touched once per wc==0 wave; reduce over g
    xss0 += __shfl_xor(xss0, 16); xss0 += __shfl_xor(xss0, 32);
    xss1 += __shfl_xor(xss1, 16); xss1 += __shfl_xor(xss1, 32);
    if (wc == 0 && g == 0) {
        xs_l[wr * 32 + sub]      = xss0;
        xs_l[wr * 32 + 16 + sub] = xss1;
    }
    __syncthreads();

    // ---- epilogue: masked mins over this wave's 64 cols ----
    float psqv[4];
    int   lab[4];
#pragma unroll
    for (int n = 0; n < 4; ++n) {
        const int col = n0 + wc * 64 + n * 16 + sub;
        psqv[n] = psq[col];
        lab[n]  = col >> 2;
    }
    const int part = nb * 2 + wc;
#pragma unroll
    for (int m = 0; m < 2; ++m) {
#pragma unroll
        for (int r = 0; r < 4; ++r) {
            const int rl = wr * 32 + m * 16 + g * 4 + r;
            const float xs = xs_l[rl];
            const int yy = y[m0 + rl];
            float d1 = BIGF, d2 = BIGF;
#pragma unroll
            for (int n = 0; n < 4; ++n) {
                const float dist = xs + psqv[n] - 2.0f * acc[m][n][r];
                if (lab[n] == yy) d1 = fminf(d1, dist);
                else              d2 = fminf(d2, dist);
            }
            for (int off = 8; off; off >>= 1) {
                d1 = fminf(d1, __shfl_xor(d1, off));
                d2 = fminf(d2, __shfl_xor(d2, off));
            }
            if (sub == 0) {
                d1p[part * NS + m0 + rl] = d1;
                d2p[part * NS + m0 + rl] = d2;
            }
        }
    }
}

__global__ __launch_bounds__(256) void finalize_kernel(
    const float* __restrict__ d1p, const float* __restrict__ d2p,
    const int* __restrict__ tval, float* __restrict__ bsum)
{
    const int row = blockIdx.x * 256 + threadIdx.x;
    float d1 = BIGF, d2 = BIGF;
#pragma unroll
    for (int p = 0; p < NPARTS; ++p) {
        d1 = fminf(d1, d1p[p * NS + row]);
        d2 = fminf(d2, d2p[p * NS + row]);
    }
    const float mu = (d1 - d2) / (d1 + d2 + EPSF);
    const float alpha = logf(1.0f + (float)tval[0]);
    float s = 1.0f / (1.0f + expf(-alpha * mu));
    for (int off = 32; off; off >>= 1) s += __shfl_down(s, off);
    __shared__ float red[4];
    if ((threadIdx.x & 63) == 0) red[threadIdx.x >> 6] = s;
    __syncthreads();
    if (threadIdx.x == 0) bsum[blockIdx.x] = red[0] + red[1] + red[2] + red[3];
}

__global__ void final_sum(const float* __restrict__ bsum, float* __restrict__ out) {
    float s = (threadIdx.x < NS / 256) ? bsum[threadIdx.x] : 0.0f;
    for (int off = 32; off; off >>= 1) s += __shfl_down(s, off);
    if (threadIdx.x == 0) out[0] = s * (1.0f / (float)NS);
}

extern "C" void kernel_launch(void* const* d_in, const int* in_sizes, int n_in,
                              void* d_out, int out_size, void* d_ws, size_t ws_size,
                              hipStream_t stream) {
    const float* x      = (const float*)d_in[0];
    const int*   y      = (const int*)d_in[1];
    const int*   tval   = (const int*)d_in[2];
    const float* protos = (const float*)d_in[3];
    float* out = (float*)d_out;

    char* ws = (char*)d_ws;
    unsigned short* pb = (unsigned short*)(ws);                    // 1 MB
    float* psq  = (float*)(ws + (size_t)NP * DD * 2);              // 2 KB
    float* d1p  = psq + NP;                                        // 256 KB
    float* d2p  = d1p + (size_t)NPARTS * NS;                       // 256 KB
    float* bsum = d2p + (size_t)NPARTS * NS;                       // 128 B

    prep_protos<<<NP, 256, 0, stream>>>(protos, pb, psq);
    glvq_fused<<<(NS / MT) * (NP / NT), 256, 0, stream>>>(x, pb, psq, y, d1p, d2p);
    finalize_kernel<<<NS / 256, 256, 0, stream>>>(d1p, d2p, tval, bsum);
    final_sum<<<1, 64, 0, stream>>>(bsum, out);
}